// Round 1
// baseline (180.353 us; speedup 1.0000x reference)
//
#include <hip/hip_runtime.h>
#include <hip/hip_bf16.h>

// Problem constants (from setup_inputs): S=128, E=16, C=256, H=1024, h=64, r=16
#define S_SEG 128
#define N_IMG 16
#define N_CH  256
#define HFULL 1024
#define HSM   64
#define MIN_PIXELS 50.0f

// ---------------------------------------------------------------------------
// Kernel 1: pool 16x16 blocks of the binary mask, threshold, emit sel bits.
// grid = (hb=64, s=128), block = 256 threads.
// Each block: 16 mask rows x 1024 cols = 64 KB read -> one u64 of sel bits.
// ---------------------------------------------------------------------------
__global__ __launch_bounds__(256) void mask_reduce(
    const float* __restrict__ masks,
    unsigned long long* __restrict__ selbits,
    float* __restrict__ den)
{
    const int hb = blockIdx.x;   // row-block 0..63
    const int s  = blockIdx.y;   // segment 0..127
    const int t  = threadIdx.x;  // 0..255

    const float4* m4 = (const float4*)(masks + (size_t)s * HFULL * HFULL
                                             + (size_t)hb * 16 * HFULL);
    float sum = 0.f;
#pragma unroll
    for (int i = 0; i < 16; ++i) {       // 16 rows; thread t owns cols [4t,4t+3]
        float4 v = m4[i * 256 + t];
        sum += (v.x + v.y) + (v.z + v.w);
    }
    // reduce groups of 4 lanes -> 16-col block sums
    sum += __shfl_xor(sum, 1);
    sum += __shfl_xor(sum, 2);
    const bool sel = (sum >= MIN_PIXELS);

    unsigned long long b = __ballot(((t & 3) == 0) && sel);

    __shared__ unsigned int bits16[4];
    const int wave = t >> 6, lane = t & 63;
    if (lane == 0) {
        unsigned int r = 0;
        for (int j = 0; j < 16; ++j)
            r |= ((unsigned int)((b >> (4 * j)) & 1ull)) << j;
        bits16[wave] = r;
    }
    __syncthreads();
    if (t == 0) {
        unsigned long long w =  (unsigned long long)bits16[0]
                             | ((unsigned long long)bits16[1] << 16)
                             | ((unsigned long long)bits16[2] << 32)
                             | ((unsigned long long)bits16[3] << 48);
        selbits[s * 64 + hb] = w;                       // bit j = sel[s][hb][j]
        atomicAdd(&den[s], (float)__popcll(w));
    }
}

// ---------------------------------------------------------------------------
// Kernel 2: num[s,c] = sum_hw emb[e,c,hw]*sel[s,hw]; out = num/den.
// Grouped by image so sam is read ~once total.
// grid = (e=16, cchunk=32), block = 256 (4 waves). Each block: 8 channels,
// all segments with image_ids[s]==e, processed 8 segments per pass.
// ---------------------------------------------------------------------------
__global__ __launch_bounds__(256) void seg_dot(
    const float* __restrict__ sam,
    const int* __restrict__ ids,
    const unsigned int* __restrict__ selbits32,   // selbits viewed as u32
    const float* __restrict__ den,
    float* __restrict__ out)
{
    const int e  = blockIdx.x;        // 0..15
    const int c0 = blockIdx.y * 8;    // first channel of this block's chunk
    const int t = threadIdx.x, wave = t >> 6, lane = t & 63;

    __shared__ int ids_l[S_SEG];
    __shared__ int list[S_SEG];
    __shared__ int nseg_s;
    __shared__ unsigned int bl32[8][128];   // 8 segs x 4096 bits
    __shared__ float den_l[8];

    if (t < S_SEG) ids_l[t] = ids[t];
    __syncthreads();
    if (t == 0) {
        int n = 0;
        for (int s = 0; s < S_SEG; ++s)
            if (ids_l[s] == e) list[n++] = s;
        nseg_s = n;
    }
    __syncthreads();
    const int n = nseg_s;
    if (n == 0) return;

    const float4* emb4 = (const float4*)(sam + (size_t)e * N_CH * HSM * HSM);

    for (int base = 0; base < n; base += 8) {
        const int kc = min(8, n - base);
        for (int i = t; i < kc * 128; i += 256) {
            const int k = i >> 7, w = i & 127;
            bl32[k][w] = selbits32[list[base + k] * 128 + w];
        }
        if (t < kc) den_l[t] = den[list[base + t]];
        __syncthreads();

#pragma unroll
        for (int r = 0; r < 2; ++r) {
            const int c = c0 + r * 4 + wave;
            float acc[8];
#pragma unroll
            for (int k = 0; k < 8; ++k) acc[k] = 0.f;

            const float4* ep = emb4 + (size_t)c * 1024;
#pragma unroll 4
            for (int j = 0; j < 16; ++j) {
                const int f4 = j * 64 + lane;           // float4 index in [0,1024)
                const float4 v = ep[f4];
                const int wi = f4 >> 3;                 // u32 word (hw/32)
                const int sh = (f4 & 7) << 2;           // nibble shift
#pragma unroll
                for (int k = 0; k < 8; ++k) {
                    const unsigned int nib = (bl32[k][wi] >> sh) & 15u;
                    float a = (nib & 1u) ? v.x : 0.f;
                    a += (nib & 2u) ? v.y : 0.f;
                    a += (nib & 4u) ? v.z : 0.f;
                    a += (nib & 8u) ? v.w : 0.f;
                    acc[k] += a;
                }
            }
#pragma unroll
            for (int k = 0; k < 8; ++k) {
                float a = acc[k];
                a += __shfl_xor(a, 32); a += __shfl_xor(a, 16);
                a += __shfl_xor(a, 8);  a += __shfl_xor(a, 4);
                a += __shfl_xor(a, 2);  a += __shfl_xor(a, 1);
                if (lane == 0 && k < kc) {
                    const int s = list[base + k];
                    out[384 + s * N_CH + c] = a / den_l[k];
                }
            }
        }
        __syncthreads();
    }
}

// ---------------------------------------------------------------------------
// Kernel 3: passthrough outputs (ids, rel ids, is_latent=0, coords).
// out layout: [0:128) ids, [128:256) rel, [256:384) zeros,
//             [384:33152) embeddings, [33152:33664) coords.
// ---------------------------------------------------------------------------
__global__ void tails(const int* __restrict__ ids,
                      const int* __restrict__ rel,
                      const float* __restrict__ coords,
                      float* __restrict__ out)
{
    const int i = blockIdx.x * 256 + threadIdx.x;
    if (i < 128)        out[i] = (float)ids[i];
    else if (i < 256)   out[i] = (float)rel[i - 128];
    else if (i < 384)   out[i] = 0.0f;
    else if (i < 896)   out[32768 + i] = coords[i - 384];  // 33152 + (i-384)
}

extern "C" void kernel_launch(void* const* d_in, const int* in_sizes, int n_in,
                              void* d_out, int out_size, void* d_ws, size_t ws_size,
                              hipStream_t stream)
{
    const float* masks  = (const float*)d_in[0];
    const float* sam    = (const float*)d_in[1];
    const int*   ids    = (const int*)d_in[2];
    const int*   rel    = (const int*)d_in[3];
    const float* coords = (const float*)d_in[4];
    float* out = (float*)d_out;

    unsigned long long* selbits = (unsigned long long*)d_ws;       // 64 KB
    float* den = (float*)((char*)d_ws + 64 * 1024);                // 512 B

    hipMemsetAsync(den, 0, S_SEG * sizeof(float), stream);

    mask_reduce<<<dim3(64, S_SEG), 256, 0, stream>>>(masks, selbits, den);
    seg_dot<<<dim3(N_IMG, 32), 256, 0, stream>>>(
        sam, ids, (const unsigned int*)selbits, den, out);
    tails<<<4, 256, 0, stream>>>(ids, rel, coords, out);
}

// Round 2
// 129.602 us; speedup vs baseline: 1.3916x; 1.3916x over previous
//
#include <hip/hip_runtime.h>
#include <hip/hip_bf16.h>

// Problem constants: S=128, E=16, C=256, H=1024, h=64, r=16
#define S_SEG 128
#define N_IMG 16
#define N_CH  256
#define HFULL 1024
#define HSM   64
#define MIN_PIXELS 50.0f

typedef float v4 __attribute__((ext_vector_type(4)));

// ---------------------------------------------------------------------------
// Kernel 1: pool 16x16 blocks of the binary mask, threshold, emit sel bits.
// grid = (hb=64, s=128), block = 256. Each block streams a contiguous 64 KB.
// Per wave: 16 block-sums -> 1 shuffle + ballot -> one u16 store. No LDS,
// no __syncthreads, no atomics. Non-temporal loads keep sam resident in L3.
// ---------------------------------------------------------------------------
__global__ __launch_bounds__(256) void mask_reduce(
    const float* __restrict__ masks,
    unsigned short* __restrict__ selb16)
{
    const int hb = blockIdx.x;   // row-block 0..63
    const int s  = blockIdx.y;   // segment 0..127
    const int t  = threadIdx.x;
    const int lane = t & 63, wave = t >> 6;

    const v4* m4 = (const v4*)(masks + (size_t)s * HFULL * HFULL
                                     + (size_t)hb * 16 * HFULL);
    float sum = 0.f;
#pragma unroll
    for (int i = 0; i < 16; ++i) {           // thread t owns cols [4t,4t+3]
        v4 v = __builtin_nontemporal_load(&m4[i * 256 + t]);
        sum += (v.x + v.y) + (v.z + v.w);
    }
    // 4-lane groups -> 16-col block sums (every lane of the group has it)
    sum += __shfl_xor(sum, 1);
    sum += __shfl_xor(sum, 2);
    // compact: lane l fetches group (l&15)'s sum so ballot bits 0..15 are the
    // 16 block flags of this wave's 16 column-blocks
    const float s2 = __shfl(sum, (lane & 15) * 4);
    const unsigned long long b = __ballot(s2 >= MIN_PIXELS);
    if (lane == 0)
        selb16[(s * 64 + hb) * 4 + wave] = (unsigned short)(b & 0xFFFFull);
}

// ---------------------------------------------------------------------------
// Kernel 2: out_emb[s,c] = (sum_hw emb[ids[s],c,hw]*sel[s,hw]) / popcount(sel).
// grid = (e=16, y=65), block = 256 (4 waves; 1 channel per wave, 4 per block).
// y==64 slice handles the passthrough tail outputs.
// Segments grouped by image; up to 16 per pass (bits in LDS), den from
// popcount in LDS -> no memset, no global atomics.
// ---------------------------------------------------------------------------
template<int NK>
__device__ __forceinline__ void do_pass(
    const v4* __restrict__ ep, int lane,
    const unsigned int (&bl)[16][128],
    const int* list, int base, int kc,
    const int* den_i, int c, float* __restrict__ out)
{
    float acc[NK];
#pragma unroll
    for (int k = 0; k < NK; ++k) acc[k] = 0.f;

#pragma unroll 4
    for (int j = 0; j < 16; ++j) {
        const int f4 = j * 64 + lane;        // float4 index in [0,1024)
        const v4 v = ep[f4];
        const int wi = f4 >> 3;              // u32 word = bitpos/32
        const int sh = (f4 & 7) << 2;        // nibble shift
#pragma unroll
        for (int k = 0; k < NK; ++k) {
            const unsigned int nib = (bl[k][wi] >> sh) & 15u;
            float a = (nib & 1u) ? v.x : 0.f;
            a += (nib & 2u) ? v.y : 0.f;
            a += (nib & 4u) ? v.z : 0.f;
            a += (nib & 8u) ? v.w : 0.f;
            acc[k] += a;
        }
    }
#pragma unroll
    for (int k = 0; k < NK; ++k) {
        float a = acc[k];
        a += __shfl_xor(a, 32); a += __shfl_xor(a, 16);
        a += __shfl_xor(a, 8);  a += __shfl_xor(a, 4);
        a += __shfl_xor(a, 2);  a += __shfl_xor(a, 1);
        if (lane == 0 && k < kc) {
            const int s = list[base + k];
            out[384 + s * N_CH + c] = a / (float)den_i[k];
        }
    }
}

__global__ __launch_bounds__(256) void seg_dot(
    const float* __restrict__ sam,
    const int* __restrict__ ids,
    const int* __restrict__ rel,
    const float* __restrict__ coords,
    const unsigned int* __restrict__ selbits32,
    float* __restrict__ out)
{
    if (blockIdx.y == 64) {                  // passthrough tails
        const int i = blockIdx.x * 256 + threadIdx.x;
        if (i < 128)        out[i] = (float)ids[i];
        else if (i < 256)   out[i] = (float)rel[i - 128];
        else if (i < 384)   out[i] = 0.0f;
        else if (i < 896)   out[32768 + i] = coords[i - 384];  // 33152+(i-384)
        return;
    }

    const int e  = blockIdx.x;               // image 0..15
    const int c  = blockIdx.y * 4 + (threadIdx.x >> 6);  // channel
    const int t = threadIdx.x, lane = t & 63;

    __shared__ int ids_l[S_SEG];
    __shared__ int list[S_SEG];
    __shared__ int nseg_s;
    __shared__ unsigned int bl32[16][128];   // 16 segs x 4096 bits
    __shared__ int den_i[16];

    if (t < S_SEG) ids_l[t] = ids[t];
    __syncthreads();
    if (t == 0) {
        int n = 0;
        for (int s = 0; s < S_SEG; ++s)
            if (ids_l[s] == e) list[n++] = s;
        nseg_s = n;
    }
    __syncthreads();
    const int n = nseg_s;
    if (n == 0) return;

    const v4* ep = (const v4*)(sam + (size_t)e * N_CH * HSM * HSM)
                 + (size_t)c * 1024;

    for (int base = 0; base < n; base += 16) {
        const int kc = min(16, n - base);
        if (t < 16) den_i[t] = 0;
        for (int i = t; i < kc * 128; i += 256) {
            const int k = i >> 7, w = i & 127;
            bl32[k][w] = selbits32[list[base + k] * 128 + w];
        }
        __syncthreads();
        {   // den[k] = popcount of segment k's 4096 bits
            const int k = t >> 4, part = t & 15;
            if (k < kc) {
                int cnt = 0;
#pragma unroll
                for (int q = 0; q < 8; ++q) cnt += __popc(bl32[k][part * 8 + q]);
                atomicAdd(&den_i[k], cnt);
            }
        }
        __syncthreads();

        if (kc <= 8) do_pass<8>(ep, lane, bl32, list, base, kc, den_i, c, out);
        else         do_pass<16>(ep, lane, bl32, list, base, kc, den_i, c, out);
        __syncthreads();
    }
}

extern "C" void kernel_launch(void* const* d_in, const int* in_sizes, int n_in,
                              void* d_out, int out_size, void* d_ws, size_t ws_size,
                              hipStream_t stream)
{
    const float* masks  = (const float*)d_in[0];
    const float* sam    = (const float*)d_in[1];
    const int*   ids    = (const int*)d_in[2];
    const int*   rel    = (const int*)d_in[3];
    const float* coords = (const float*)d_in[4];
    float* out = (float*)d_out;

    unsigned short* selb16 = (unsigned short*)d_ws;    // 64 KB of sel bits

    mask_reduce<<<dim3(64, S_SEG), 256, 0, stream>>>(masks, selb16);
    seg_dot<<<dim3(N_IMG, 65), 256, 0, stream>>>(
        sam, ids, rel, coords, (const unsigned int*)d_ws, out);
}

// Round 3
// 106.903 us; speedup vs baseline: 1.6871x; 1.2123x over previous
//
#include <hip/hip_runtime.h>
#include <hip/hip_bf16.h>

// Problem constants: S=128, E=16, C=256, H=1024, h=64, r=16
#define S_SEG 128
#define N_IMG 16
#define N_CH  256
#define HFULL 1024
#define HSM   64
#define MIN_PIXELS 50.0f

typedef float v4 __attribute__((ext_vector_type(4)));

// ---------------------------------------------------------------------------
// Kernel 1 (UNCHANGED from round 2): pool 16x16 blocks, threshold, emit bits.
// grid = (hb=64, s=128), block = 256. Each block streams a contiguous 64 KB.
// ---------------------------------------------------------------------------
__global__ __launch_bounds__(256) void mask_reduce(
    const float* __restrict__ masks,
    unsigned short* __restrict__ selb16)
{
    const int hb = blockIdx.x;   // row-block 0..63 (== sel row i)
    const int s  = blockIdx.y;   // segment 0..127
    const int t  = threadIdx.x;
    const int lane = t & 63, wave = t >> 6;

    const v4* m4 = (const v4*)(masks + (size_t)s * HFULL * HFULL
                                     + (size_t)hb * 16 * HFULL);
    float sum = 0.f;
#pragma unroll
    for (int i = 0; i < 16; ++i) {
        v4 v = __builtin_nontemporal_load(&m4[i * 256 + t]);
        sum += (v.x + v.y) + (v.z + v.w);
    }
    sum += __shfl_xor(sum, 1);
    sum += __shfl_xor(sum, 2);
    const float s2 = __shfl(sum, (lane & 15) * 4);
    const unsigned long long b = __ballot(s2 >= MIN_PIXELS);
    if (lane == 0)
        selb16[(s * 64 + hb) * 4 + wave] = (unsigned short)(b & 0xFFFFull);
}

// ---------------------------------------------------------------------------
// Kernel 2 (REWRITTEN): out_emb[s,c] = sum(emb[ids[s],c,:]*sel[s,:]) / den[s].
// grid = (e=16, y=65), block = 256 (4 waves, 1 channel each). y==64: tails.
// Parallel ballot-prefix list build; AND-word fast path exploits dense sel.
// ---------------------------------------------------------------------------
__global__ __launch_bounds__(256) void seg_dot(
    const float* __restrict__ sam,
    const int* __restrict__ ids,
    const int* __restrict__ rel,
    const float* __restrict__ coords,
    const unsigned int* __restrict__ selbits32,
    float* __restrict__ out)
{
    if (blockIdx.y == 64) {                  // passthrough tails
        const int i = blockIdx.x * 256 + threadIdx.x;
        if (i < 128)        out[i] = (float)ids[i];
        else if (i < 256)   out[i] = (float)rel[i - 128];
        else if (i < 384)   out[i] = 0.0f;
        else if (i < 896)   out[32768 + i] = coords[i - 384];  // 33152+(i-384)
        return;
    }

    const int e = blockIdx.x;
    const int t = threadIdx.x, lane = t & 63, wave = t >> 6;
    const int c = blockIdx.y * 4 + wave;     // this wave's channel

    __shared__ int list[S_SEG];
    __shared__ int wcnt[4];
    __shared__ unsigned int bl32[16][128];   // 16 segs x 4096 bits
    __shared__ unsigned int andw[128];       // AND over the 16 segs
    __shared__ int den_i[16];

    // ---- parallel list build: segments s with ids[s]==e, in order ----
    const int my = (t < S_SEG) ? ids[t] : -1;
    const bool hit = (my == e);
    const unsigned long long m = __ballot(hit);
    if (lane == 0) wcnt[wave] = __popcll(m);
    __syncthreads();
    const int n = wcnt[0] + wcnt[1];
    if (n == 0) return;
    if (hit) {
        const int pre = __popcll(m & ((1ull << lane) - 1ull));
        list[(wave == 1 ? wcnt[0] : 0) + pre] = t;
    }
    __syncthreads();

    const v4* ep = (const v4*)(sam + (size_t)e * N_CH * HSM * HSM)
                 + (size_t)c * 1024;

    for (int base = 0; base < n; base += 16) {
        const int kc = min(16, n - base);
        if (t < 16) den_i[t] = 0;
        for (int i = t; i < 16 * 128; i += 256) {
            const int k = i >> 7, w = i & 127;
            bl32[k][w] = (k < kc) ? selbits32[list[base + k] * 128 + w]
                                  : 0xFFFFFFFFu;   // pad: never triggers slow path
        }
        __syncthreads();
        if (t < 128) {                       // AND across the 16 segments
            unsigned int a = 0xFFFFFFFFu;
#pragma unroll
            for (int k = 0; k < 16; ++k) a &= bl32[k][t];
            andw[t] = a;
        }
        {                                    // den[k] = popcount(seg k bits)
            const int k = t >> 4, part = t & 15;
            int cnt = 0;
#pragma unroll
            for (int q = 0; q < 8; ++q) cnt += __popc(bl32[k][part * 8 + q]);
            atomicAdd(&den_i[k], cnt);
        }
        __syncthreads();

        // ---- accumulate: common sum + rare per-segment corrections ----
        float acc_c = 0.f;
        float corr[16];
#pragma unroll
        for (int k = 0; k < 16; ++k) corr[k] = 0.f;
        bool slow = false;

#pragma unroll
        for (int j = 0; j < 16; ++j) {
            const int f4 = j * 64 + lane;    // float4 index in [0,1024)
            const v4 v = ep[f4];
            const int wi = f4 >> 3;
            const int sh = (f4 & 7) << 2;
            acc_c += (v.x + v.y) + (v.z + v.w);
            const unsigned int na = (andw[wi] >> sh) & 15u;
            if (__any(na != 15u)) {          // wave-uniform, rare
                slow = true;
#pragma unroll
                for (int k = 0; k < 16; ++k) {
                    const unsigned int nib = bl32[k][wi] >> sh;
                    float d = (nib & 1u) ? 0.f : v.x;
                    d += (nib & 2u) ? 0.f : v.y;
                    d += (nib & 4u) ? 0.f : v.z;
                    d += (nib & 8u) ? 0.f : v.w;
                    corr[k] -= d;            // subtract unselected pixels
                }
            }
        }

        float ar = acc_c;
        ar += __shfl_xor(ar, 32); ar += __shfl_xor(ar, 16);
        ar += __shfl_xor(ar, 8);  ar += __shfl_xor(ar, 4);
        ar += __shfl_xor(ar, 2);  ar += __shfl_xor(ar, 1);

        if (!__any(slow)) {                  // dense case: one value fits all
            if (lane < kc)
                out[384 + list[base + lane] * N_CH + c]
                    = ar / (float)den_i[lane];
        } else {
#pragma unroll
            for (int k = 0; k < 16; ++k) {
                float a = corr[k];
                a += __shfl_xor(a, 32); a += __shfl_xor(a, 16);
                a += __shfl_xor(a, 8);  a += __shfl_xor(a, 4);
                a += __shfl_xor(a, 2);  a += __shfl_xor(a, 1);
                if (lane == 0 && k < kc)
                    out[384 + list[base + k] * N_CH + c]
                        = (ar + a) / (float)den_i[k];
            }
        }
        __syncthreads();
    }
}

extern "C" void kernel_launch(void* const* d_in, const int* in_sizes, int n_in,
                              void* d_out, int out_size, void* d_ws, size_t ws_size,
                              hipStream_t stream)
{
    const float* masks  = (const float*)d_in[0];
    const float* sam    = (const float*)d_in[1];
    const int*   ids    = (const int*)d_in[2];
    const int*   rel    = (const int*)d_in[3];
    const float* coords = (const float*)d_in[4];
    float* out = (float*)d_out;

    unsigned short* selb16 = (unsigned short*)d_ws;    // 64 KB of sel bits

    mask_reduce<<<dim3(64, S_SEG), 256, 0, stream>>>(masks, selb16);
    seg_dot<<<dim3(N_IMG, 65), 256, 0, stream>>>(
        sam, ids, rel, coords, (const unsigned int*)d_ws, out);
}